// Round 5
// baseline (331.213 us; speedup 1.0000x reference)
//
#include <hip/hip_runtime.h>
#include <hip/hip_bf16.h>
#include <stdint.h>

typedef unsigned short u16;
typedef short bf16x8 __attribute__((ext_vector_type(8)));
typedef u16   u16x8  __attribute__((ext_vector_type(8)));
typedef u16   u16x4  __attribute__((ext_vector_type(4)));
typedef float f32x4  __attribute__((ext_vector_type(4)));

__device__ inline u16 f2bf(float f) {
    uint32_t u = __builtin_bit_cast(uint32_t, f);
    uint32_t r = (u + 0x7FFFu + ((u >> 16) & 1u)) >> 16;
    return (u16)r;
}

__device__ inline void gload16(const void* g, void* l) {
    __builtin_amdgcn_global_load_lds((const __attribute__((address_space(1))) void*)g,
                                     (__attribute__((address_space(3))) void*)l, 16, 0, 0);
}

__device__ inline void pin_barrier() {
    __builtin_amdgcn_sched_barrier(0);
    __builtin_amdgcn_s_barrier();
    __builtin_amdgcn_sched_barrier(0);
}

#define MFMA16(a, b, c) __builtin_amdgcn_mfma_f32_16x16x32_bf16((a), (b), (c), 0, 0, 0)

// ---------------- prep: gather even rows of x, cast to bf16 -----------------
__global__ __launch_bounds__(256) void k_prep_xe(const float* __restrict__ x,
                                                 u16* __restrict__ xe) {
    int row = blockIdx.x;              // 0..8191
    int b = row >> 12, tt = row & 4095;
    const float* src = x + ((size_t)b * 8192 + 2 * (size_t)tt) * 1024;
    float4 v = ((const float4*)src)[threadIdx.x];
    u16x4 o = { f2bf(v.x), f2bf(v.y), f2bf(v.z), f2bf(v.w) };
    *(u16x4*)(xe + (size_t)row * 1024 + threadIdx.x * 4) = o;
}

// ---------------- prep: transpose + cast weights to B^T layout --------------
__global__ __launch_bounds__(256) void k_transpose_cast(
    const float* __restrict__ src, u16* __restrict__ dst,
    int srcCols, size_t srcLayerStride, int dstStride, int dstRowPer, int dstColPer) {
    int k0 = blockIdx.x * 64, e0 = blockIdx.y * 64, layer = blockIdx.z;
    const float* s = src + (size_t)layer * srcLayerStride;
    __shared__ u16 T[64][66];
    int t = threadIdx.x;
#pragma unroll
    for (int p = 0; p < 16; ++p) {
        int l = p * 256 + t;
        int kl = l >> 6, el = l & 63;
        T[kl][el] = f2bf(s[(size_t)(k0 + kl) * srcCols + e0 + el]);
    }
    __syncthreads();
    int rowBase = layer * dstRowPer + e0;
    int colBase = layer * dstColPer + k0;
#pragma unroll
    for (int p = 0; p < 16; ++p) {
        int l = p * 256 + t;
        int eo = l >> 6, ko = l & 63;
        dst[(size_t)(rowBase + eo) * dstStride + colBase + ko] = T[ko][eo];
    }
}

// ====== 256xBN fine-phase pipelined GEMM: C = A[M,K] @ BT[N,K]^T + bias =====
// BK=32, 4-deep circular LDS buffers, global_load_lds staging with lookahead 3,
// 2 phases/tile (BN=256) or 1 (BN=128), 16 MFMA per phase, counted vmcnt(2*NL)
// once per tile (never 0 in-loop), setprio around MFMA clusters.
// LDS swizzle: tile rows 64B, chunk16 ^= (row>>1)&3 (2-way max on ds_read_b128),
// applied as inverse-swizzled GLOBAL source + swizzled ds_read (linear lds dest).
// Requires: K%128==0, M%256==0, N%BN==0, grid%8==0.
template <int BN, bool BF16OUT>
__global__ __launch_bounds__(512, 2) void k_gemm3(
    const u16* __restrict__ A, const u16* __restrict__ B, void* __restrict__ C,
    const float* __restrict__ bias0, const float* __restrict__ bias1,
    const float* __restrict__ bias2, int K, int lda, int ldb, int ldc,
    int gxmask, int gxshift) {
    constexpr int WN = BN / 64;          // waves along N (4 or 2)
    constexpr int WM = 8 / WN;           // waves along M (2 or 4)
    constexpr int MFRAG = 16 / WM;       // m-frags per wave (8 or 4)
    constexpr int PH = MFRAG / 4;        // phases per tile (2 or 1)
    constexpr int NLB = BN / 128;        // B gloads per tile (2 or 1)
    constexpr int NL = 2 + NLB;          // gloads per thread per tile
    constexpr int BUFSZ = 16384 + BN * 64;

    __shared__ __align__(16) char smem[131072];
    const int tid = threadIdx.x, lane = tid & 63, wave = tid >> 6;
    const int wr = wave / WN, wc = wave % WN;

    // bijective XCD swizzle (grid multiple of 8)
    const int nwg = gridDim.x, bid = blockIdx.x;
    const int cpx = nwg >> 3;
    const int swz = (bid & 7) * cpx + (bid >> 3);
    const int bx = swz & gxmask, by = swz >> gxshift;
    const int row0 = bx << 8, col0 = by * BN;

    const size_t lda2 = (size_t)lda * 2, ldb2 = (size_t)ldb * 2;
    // staging source (inverse-swizzled): thread covers LDS row r4=(tid>>2)(+128),
    // slot tid&3; src chunk = (lane&3) ^ ((lane>>3)&3)
    const int r4 = tid >> 2;
    const int cSw = ((lane & 3) ^ ((lane >> 3) & 3)) * 16;
    const char* pA0 = (const char*)A + (size_t)(row0 + r4) * lda2 + cSw;
    const char* pA1 = pA0 + (size_t)128 * lda2;
    const char* pB0 = (const char*)B + (size_t)(col0 + r4) * ldb2 + cSw;
    const char* pB1 = pB0 + (size_t)128 * ldb2;

#define STAGE_A(sb, kof) do { \
        gload16(pA0 + (kof), (sb) + wave * 1024); \
        gload16(pA1 + (kof), (sb) + 8192 + wave * 1024); } while (0)
#define STAGE_B(sb, kof) do { \
        gload16(pB0 + (kof), (sb) + 16384 + wave * 1024); \
        if constexpr (NLB == 2) gload16(pB1 + (kof), (sb) + 24576 + wave * 1024); \
    } while (0)

    auto WAIT_VM2NL = [] {
        if constexpr (NL == 4) asm volatile("s_waitcnt vmcnt(8)" ::: "memory");
        else                   asm volatile("s_waitcnt vmcnt(6)" ::: "memory");
    };

    // per-lane swizzled ds_read offset: row=lane&15, chunk=lane>>4,
    // byte = row*64 + (chunk*16 ^ (((row>>1)&3)<<4))
    const int lane_off = (lane & 15) * 64 +
                         (((lane >> 4) << 4) ^ ((((lane & 15) >> 1) & 3) << 4));

    f32x4 acc[8][4] = {};
    const int nt = K >> 5;

    char* const BUF0 = smem;
    char* const BUF1 = smem + BUFSZ;
    char* const BUF2 = smem + 2 * BUFSZ;
    char* const BUF3 = smem + 3 * BUFSZ;

    // prologue: stage tiles 0,1,2; retire tile 0 (vmcnt leaves 2 tiles in flight)
    STAGE_A(BUF0, 0);   STAGE_B(BUF0, 0);
    STAGE_A(BUF1, 64);  STAGE_B(BUF1, 64);
    STAGE_A(BUF2, 128); STAGE_B(BUF2, 128);
    __builtin_amdgcn_sched_barrier(0);
    WAIT_VM2NL();
    pin_barrier();

#define TILE_BODY(qb, sb, ts) do { \
        const char* aRd = (qb) + wr * (MFRAG * 1024) + lane_off; \
        const char* bRd = (qb) + 16384 + wc * 4096 + lane_off; \
        const size_t kof = (size_t)(ts) * 64; \
        bf16x8 bg[4], af[4]; \
        _Pragma("unroll") for (int n = 0; n < 4; ++n) \
            bg[n] = *(const bf16x8*)(bRd + n * 1024); \
        _Pragma("unroll") for (int m = 0; m < 4; ++m) \
            af[m] = *(const bf16x8*)(aRd + m * 1024); \
        STAGE_A(sb, kof); \
        if constexpr (PH == 1) { STAGE_B(sb, kof); \
            __builtin_amdgcn_sched_barrier(0); WAIT_VM2NL(); } \
        pin_barrier(); \
        __builtin_amdgcn_s_setprio(1); \
        _Pragma("unroll") for (int m = 0; m < 4; ++m) \
            _Pragma("unroll") for (int n = 0; n < 4; ++n) \
                acc[m][n] = MFMA16(af[m], bg[n], acc[m][n]); \
        __builtin_amdgcn_s_setprio(0); \
        pin_barrier(); \
        if constexpr (PH == 2) { \
            bf16x8 af2[4]; \
            _Pragma("unroll") for (int m = 0; m < 4; ++m) \
                af2[m] = *(const bf16x8*)(aRd + (4 + m) * 1024); \
            STAGE_B(sb, kof); \
            __builtin_amdgcn_sched_barrier(0); WAIT_VM2NL(); \
            pin_barrier(); \
            __builtin_amdgcn_s_setprio(1); \
            _Pragma("unroll") for (int m = 0; m < 4; ++m) \
                _Pragma("unroll") for (int n = 0; n < 4; ++n) \
                    acc[4 + m][n] = MFMA16(af2[m], bg[n], acc[4 + m][n]); \
            __builtin_amdgcn_s_setprio(0); \
            pin_barrier(); \
        } \
    } while (0)

    for (int t = 0; t < nt; t += 4) {
        int ts0 = (t + 3 < nt) ? t + 3 : nt - 1;
        int ts1 = (t + 4 < nt) ? t + 4 : nt - 1;
        int ts2 = (t + 5 < nt) ? t + 5 : nt - 1;
        int ts3 = (t + 6 < nt) ? t + 6 : nt - 1;
        TILE_BODY(BUF0, BUF3, ts0);
        TILE_BODY(BUF1, BUF0, ts1);
        TILE_BODY(BUF2, BUF1, ts2);
        TILE_BODY(BUF3, BUF2, ts3);
    }
#undef TILE_BODY
#undef STAGE_A
#undef STAGE_B

    // ---- epilogue: LDS-restage -> full-line coalesced stores ----
    {
        char* cst = smem;
        const int g4 = (lane >> 4) << 2, cl = lane & 15;
        // drain dead prefetches before overwriting LDS
        __builtin_amdgcn_sched_barrier(0);
        asm volatile("s_waitcnt vmcnt(0)" ::: "memory");
        pin_barrier();
#pragma unroll
        for (int n = 0; n < 4; ++n) {
            int col = wc * 64 + n * 16 + cl;
            float bs = bias0[col0 + col];
            if (bias1) bs += bias1[col0 + col];
            if (bias2) bs += bias2[col0 + col];
#pragma unroll
            for (int m = 0; m < MFRAG; ++m) {
#pragma unroll
                for (int r = 0; r < 4; ++r) {
                    int row = wr * (MFRAG * 16) + m * 16 + g4 + r;
                    float v = acc[m][n][r] + bs;
                    if (BF16OUT) {
                        int scol = col ^ (((row >> 2) & 3) << 3);
                        *(u16*)(cst + row * 512 + scol * 2) = f2bf(v);
                    } else {
                        int scol = col ^ (((row >> 2) & 3) << 2);
                        *(float*)(cst + row * 512 + scol * 4) = v;
                    }
                }
            }
        }
        pin_barrier();
        const int esz = BF16OUT ? 2 : 4;
#pragma unroll
        for (int it = 0; it < 16; ++it) {
            int id = it * 512 + tid;       // 16B chunk: row*32 + c16
            int row = id >> 5, c16 = id & 31;
            int sc16 = c16 ^ ((row >> 2) & 3);
            u16x8 v = *(const u16x8*)(cst + row * 512 + sc16 * 16);
            char* dst = (char*)C + ((size_t)(row0 + row) * ldc + col0) * esz + c16 * 16;
            *(u16x8*)dst = v;
        }
    }
}

// ---------------- attention: one block per (b, segment, head) ---------------
template <int S>
__global__ __launch_bounds__(256) void k_attn(const u16* __restrict__ qkv,
                                              u16* __restrict__ ab, int layer) {
    constexpr int NCT = S / 16;
    constexpr int RPW = (S == 32) ? 1 : S / 64;
    constexpr int ACTIVE = (S == 32) ? 2 : 4;
    constexpr int KST = S / 32;
    constexpr int VSTRIDE = 2 * S;
    constexpr int VMASK = VSTRIDE / 16 - 1;

    __shared__ __align__(16) char KS[S * 128];
    __shared__ __align__(16) char VTS[64 * VSTRIDE];
    __shared__ __align__(16) char PS[S * VSTRIDE];

    const int per_b = (4096 / S) * 16;
    const int b = blockIdx.x / per_b;
    const int r0 = blockIdx.x % per_b;
    const int n = r0 >> 4, h = r0 & 15;
    const int token0 = b * 4096 + n * S;
    const int colQ = layer * 3072 + h * 64;
    const int tid = threadIdx.x, lane = tid & 63, wave = tid >> 6;

    constexpr int CHUNKS = S / 32;
#pragma unroll
    for (int c = 0; c < CHUNKS; ++c) {
        int lc = c * 256 + tid;
        int row = lc >> 3, off = (lc & 7) * 16;
        const char* base = (const char*)qkv + ((size_t)(token0 + row) * 9216 + colQ) * 2 + off;
        u16x8 kv = *(const u16x8*)(base + 1024 * 2);
        *(u16x8*)(KS + row * 128 + (off ^ ((row & 7) << 4))) = kv;
        u16x8 vv = *(const u16x8*)(base + 2048 * 2);
        int cb = off >> 1;
#pragma unroll
        for (int e = 0; e < 8; ++e) {
            int col = cb + e;
            *(u16*)(VTS + col * VSTRIDE + ((row * 2) ^ ((col & VMASK) << 4))) = vv[e];
        }
    }
    __syncthreads();

    f32x4 sacc[RPW][NCT] = {};
    if (wave < ACTIVE) {
#pragma unroll
        for (int rl = 0; rl < RPW; ++rl) {
            int rt = wave * RPW + rl;
#pragma unroll
            for (int ks2 = 0; ks2 < 2; ++ks2) {
                int qrow = token0 + rt * 16 + (lane & 15);
                int kbyte = ks2 * 64 + ((lane >> 4) << 4);
                bf16x8 aq = *(const bf16x8*)((const char*)qkv +
                              ((size_t)qrow * 9216 + colQ) * 2 + kbyte);
#pragma unroll
                for (int ct = 0; ct < NCT; ++ct) {
                    int krow = ct * 16 + (lane & 15);
                    bf16x8 bk = *(const bf16x8*)(KS + krow * 128 + (kbyte ^ ((krow & 7) << 4)));
                    sacc[rl][ct] = MFMA16(aq, bk, sacc[rl][ct]);
                }
            }
        }
#pragma unroll
        for (int rl = 0; rl < RPW; ++rl) {
            int rt = wave * RPW + rl;
#pragma unroll
            for (int r = 0; r < 4; ++r) {
                float vals[NCT];
                float m = -1e30f;
#pragma unroll
                for (int ct = 0; ct < NCT; ++ct) {
                    vals[ct] = sacc[rl][ct][r] * 0.125f;
                    m = fmaxf(m, vals[ct]);
                }
#pragma unroll
                for (int d = 1; d < 16; d <<= 1) m = fmaxf(m, __shfl_xor(m, d, 64));
                float sum = 0.f;
#pragma unroll
                for (int ct = 0; ct < NCT; ++ct) {
                    float p = exp2f((vals[ct] - m) * 1.44269504f);
                    vals[ct] = p;
                    sum += p;
                }
#pragma unroll
                for (int d = 1; d < 16; d <<= 1) sum += __shfl_xor(sum, d, 64);
                float inv = 1.0f / sum;
                int row = rt * 16 + ((lane >> 4) << 2) + r;
#pragma unroll
                for (int ct = 0; ct < NCT; ++ct) {
                    int col = ct * 16 + (lane & 15);
                    *(u16*)(PS + row * VSTRIDE + ((col * 2) ^ ((row & VMASK) << 4))) =
                        f2bf(vals[ct] * inv);
                }
            }
        }
    }
    __syncthreads();

    if (wave < ACTIVE) {
        const int colA = layer * 1024 + h * 64;
#pragma unroll
        for (int rl = 0; rl < RPW; ++rl) {
            int rt = wave * RPW + rl;
            f32x4 oacc[4] = {};
#pragma unroll
            for (int ks2 = 0; ks2 < KST; ++ks2) {
                int kbyte = ks2 * 64 + ((lane >> 4) << 4);
                int prow = rt * 16 + (lane & 15);
                bf16x8 ap = *(const bf16x8*)(PS + prow * VSTRIDE + (kbyte ^ ((prow & VMASK) << 4)));
#pragma unroll
                for (int ct = 0; ct < 4; ++ct) {
                    int vcol = ct * 16 + (lane & 15);
                    bf16x8 bv = *(const bf16x8*)(VTS + vcol * VSTRIDE + (kbyte ^ ((vcol & VMASK) << 4)));
                    oacc[ct] = MFMA16(ap, bv, oacc[ct]);
                }
            }
#pragma unroll
            for (int ct = 0; ct < 4; ++ct) {
#pragma unroll
                for (int r = 0; r < 4; ++r) {
                    int row = token0 + rt * 16 + ((lane >> 4) << 2) + r;
                    int col = colA + ct * 16 + (lane & 15);
                    ab[(size_t)row * 3072 + col] = f2bf(oacc[ct][r]);
                }
            }
        }
    }
}

// ---------------------------------------------------------------------------
extern "C" void kernel_launch(void* const* d_in, const int* in_sizes, int n_in,
                              void* d_out, int out_size, void* d_ws, size_t ws_size,
                              hipStream_t stream) {
    const float* x    = (const float*)d_in[0];
    const float* Wqkv = (const float*)d_in[1];
    const float* bqkv = (const float*)d_in[2];
    const float* Wo   = (const float*)d_in[3];
    const float* bo   = (const float*)d_in[4];

    char* ws = (char*)d_ws;
    u16* XE    = (u16*)(ws);                       // [8192][1024]
    u16* WQKVT = (u16*)(ws + 16777216);            // [9216][1024]
    u16* WOT   = (u16*)(ws + 35651584);            // [1024][3072]
    u16* QKVB  = (u16*)(ws + 41943040);            // [8192][9216]
    u16* ABUF  = (u16*)(ws + 192937984);           // [8192][3072]

    k_prep_xe<<<8192, 256, 0, stream>>>(x, XE);
    k_transpose_cast<<<dim3(16, 48, 3), 256, 0, stream>>>(
        Wqkv, WQKVT, 3072, (size_t)1024 * 3072, 1024, 3072, 0);
    k_transpose_cast<<<dim3(16, 16, 3), 256, 0, stream>>>(
        Wo, WOT, 1024, (size_t)1024 * 1024, 3072, 0, 1024);

    // QKV projection for all 3 layers: [8192,1024] @ [1024,9216]
    // grid = 32 x 36 = 1152 blocks (bx fastest: mask 31, shift 5)
    k_gemm3<256, true><<<dim3(1152), 512, 0, stream>>>(
        XE, WQKVT, QKVB, bqkv, nullptr, nullptr, 1024, 1024, 1024, 9216, 31, 5);

    // dilated segment attention per layer
    k_attn<32><<<4096, 256, 0, stream>>>(QKVB, ABUF, 0);
    k_attn<64><<<2048, 256, 0, stream>>>(QKVB, ABUF, 1);
    k_attn<128><<<1024, 256, 0, stream>>>(QKVB, ABUF, 2);

    // fused output projection + layer sum: [8192,3072] @ [3072,1024]
    // grid = 32 x 8 = 256 blocks
    k_gemm3<128, false><<<dim3(256), 512, 0, stream>>>(
        ABUF, WOT, d_out, bo, bo + 1024, bo + 2048, 3072, 3072, 3072, 1024, 31, 5);
}

// Round 6
// 323.551 us; speedup vs baseline: 1.0237x; 1.0237x over previous
//
#include <hip/hip_runtime.h>
#include <hip/hip_bf16.h>
#include <stdint.h>

typedef unsigned short u16;
typedef short bf16x8 __attribute__((ext_vector_type(8)));
typedef u16   u16x8  __attribute__((ext_vector_type(8)));
typedef u16   u16x4  __attribute__((ext_vector_type(4)));
typedef float f32x4  __attribute__((ext_vector_type(4)));

__device__ inline u16 f2bf(float f) {
    uint32_t u = __builtin_bit_cast(uint32_t, f);
    uint32_t r = (u + 0x7FFFu + ((u >> 16) & 1u)) >> 16;
    return (u16)r;
}

__device__ inline void gload16(const void* g, void* l) {
    __builtin_amdgcn_global_load_lds((const __attribute__((address_space(1))) void*)g,
                                     (__attribute__((address_space(3))) void*)l, 16, 0, 0);
}

__device__ inline void pin_barrier() {
    __builtin_amdgcn_sched_barrier(0);
    __builtin_amdgcn_s_barrier();
    __builtin_amdgcn_sched_barrier(0);
}

#define MFMA16(a, b, c) __builtin_amdgcn_mfma_f32_16x16x32_bf16((a), (b), (c), 0, 0, 0)

// ---------------- prep: gather even rows of x, cast to bf16 -----------------
__global__ __launch_bounds__(256) void k_prep_xe(const float* __restrict__ x,
                                                 u16* __restrict__ xe) {
    int row = blockIdx.x;              // 0..8191
    int b = row >> 12, tt = row & 4095;
    const float* src = x + ((size_t)b * 8192 + 2 * (size_t)tt) * 1024;
    float4 v = ((const float4*)src)[threadIdx.x];
    u16x4 o = { f2bf(v.x), f2bf(v.y), f2bf(v.z), f2bf(v.w) };
    *(u16x4*)(xe + (size_t)row * 1024 + threadIdx.x * 4) = o;
}

// ---------------- prep: transpose + cast weights to B^T layout --------------
__global__ __launch_bounds__(256) void k_transpose_cast(
    const float* __restrict__ src, u16* __restrict__ dst,
    int srcCols, size_t srcLayerStride, int dstStride, int dstRowPer, int dstColPer) {
    int k0 = blockIdx.x * 64, e0 = blockIdx.y * 64, layer = blockIdx.z;
    const float* s = src + (size_t)layer * srcLayerStride;
    __shared__ u16 T[64][66];
    int t = threadIdx.x;
#pragma unroll
    for (int p = 0; p < 16; ++p) {
        int l = p * 256 + t;
        int kl = l >> 6, el = l & 63;
        T[kl][el] = f2bf(s[(size_t)(k0 + kl) * srcCols + e0 + el]);
    }
    __syncthreads();
    int rowBase = layer * dstRowPer + e0;
    int colBase = layer * dstColPer + k0;
#pragma unroll
    for (int p = 0; p < 16; ++p) {
        int l = p * 256 + t;
        int eo = l >> 6, ko = l & 63;
        dst[(size_t)(rowBase + eo) * dstStride + colBase + ko] = T[ko][eo];
    }
}

// ====== 256xBN BK=64 GEMM, 1 barrier/tile, reg-pipelined phases =============
// C = A[M,K] @ BT[N,K]^T + bias. 2 LDS buffers; tile t reads buf[t&1] while
// tile t+1 stages into buf[~t&1] (gload_lds, issued in phases 0-1, waited by
// the single end-of-tile vmcnt(0)+barrier). Within a tile: 4 (or 2) phases of
// 16 MFMA; each phase's ds_reads are issued BEFORE the previous MFMA cluster
// so the compiler emits counted lgkmcnt and LDS service hides under MFMA.
// Swizzle: LDS row = 128B, 16B-slot ^= (row&7); inverse-swizzle on the global
// staging source (linear gload_lds dest), swizzled ds_read. 2 lanes/bank.
// Requires: K%64==0, M%256==0, N%BN==0, grid%8==0.
template <int BN, bool BF16OUT>
__global__ __launch_bounds__(512, 2) void k_gemm4(
    const u16* __restrict__ A, const u16* __restrict__ B, void* __restrict__ C,
    const float* __restrict__ bias0, const float* __restrict__ bias1,
    const float* __restrict__ bias2, int K, int lda, int ldb, int ldc,
    int gxmask, int gxshift) {
    constexpr int WN = BN / 64;            // waves along N (4 or 2)
    constexpr int WM = 8 / WN;             // waves along M (2 or 4)
    constexpr int MFRAG = 256 / (WM * 16); // m-frags per wave (8 or 4)
    constexpr int NB = BN / 64;            // B stage-issues per tile (4 or 2)
    constexpr int BUFSZ = 32768 + BN * 128;

    __shared__ __align__(16) char smem[131072];
    const int tid = threadIdx.x, lane = tid & 63, wave = tid >> 6;
    const int wr = wave / WN, wc = wave % WN;

    // bijective XCD swizzle (grid multiple of 8)
    const int nwg = gridDim.x, bid = blockIdx.x;
    const int cpx = nwg >> 3;
    const int swz = (bid & 7) * cpx + (bid >> 3);
    const int bx = swz & gxmask, by = swz >> gxshift;
    const int row0 = bx << 8, col0 = by * BN;

    const size_t lda2 = (size_t)lda * 2, ldb2 = (size_t)ldb * 2;
    // staging: wave-issue i covers rows i*64 + wave*8 .. +8; lane l -> local
    // row l>>3, LDS slot l&7 holding global 16B-chunk (l&7)^(l>>3).
    const char* pA0 = (const char*)A +
        (size_t)(row0 + wave * 8 + (lane >> 3)) * lda2 + ((lane & 7) ^ (lane >> 3)) * 16;
    const char* pB0 = (const char*)B +
        (size_t)(col0 + wave * 8 + (lane >> 3)) * ldb2 + ((lane & 7) ^ (lane >> 3)) * 16;

#define STA(i, sb, kof) gload16(pA0 + (size_t)(i) * 64 * lda2 + (kof), (sb) + ((i) * 8 + wave) * 1024)
#define STB(i, sb, kof) gload16(pB0 + (size_t)(i) * 64 * ldb2 + (kof), (sb) + 32768 + ((i) * 8 + wave) * 1024)

    // frag ds_read offsets: row = ...+ (lane&15); slot = (kh*4 + lane>>4) ^ (row&7)
    const int la = lane & 15, lg = lane >> 4, l7 = lane & 7;
    const int offK0 = la * 128 + ((lg ^ l7) << 4);
    const int offK1 = la * 128 + (((4 + lg) ^ l7) << 4);

    f32x4 acc[MFRAG][4] = {};
    const int nt = K >> 6;

    char* const BUF0 = smem;
    char* const BUF1 = smem + BUFSZ;

    // prologue: stage tile 0 into BUF0, drain once
    {
#pragma unroll
        for (int i = 0; i < 4; ++i) STA(i, BUF0, 0);
#pragma unroll
        for (int i = 0; i < NB; ++i) STB(i, BUF0, 0);
        __builtin_amdgcn_sched_barrier(0);
        asm volatile("s_waitcnt vmcnt(0)" ::: "memory");
        pin_barrier();
    }

    for (int t = 0; t < nt; ++t) {
        char* rq = (t & 1) ? BUF1 : BUF0;
        char* sq = (t & 1) ? BUF0 : BUF1;
        const bool st = (t + 1 < nt);
        const size_t kof = (size_t)(t + 1) * 128;
        const char* aB = rq + wr * (MFRAG * 2048);
        const char* bB = rq + 32768 + wc * 8192;

        bf16x8 af[4], ag[4], b0[4], b1[4];
        // ---- phase 0 reads (kh0) + all stage issues + phase 1/2 reads ----
#pragma unroll
        for (int n = 0; n < 4; ++n) b0[n] = *(const bf16x8*)(bB + n * 2048 + offK0);
#pragma unroll
        for (int m = 0; m < 4; ++m) af[m] = *(const bf16x8*)(aB + m * 2048 + offK0);
        if (st) { STA(0, sq, kof); STA(1, sq, kof); }
        if constexpr (MFRAG == 8) {
#pragma unroll
            for (int m = 0; m < 4; ++m)
                ag[m] = *(const bf16x8*)(aB + 8192 + m * 2048 + offK0);
        } else {
#pragma unroll
            for (int m = 0; m < 4; ++m)
                ag[m] = *(const bf16x8*)(aB + m * 2048 + offK1);
        }
#pragma unroll
        for (int n = 0; n < 4; ++n) b1[n] = *(const bf16x8*)(bB + n * 2048 + offK1);
        if (st) {
            STA(2, sq, kof); STA(3, sq, kof);
#pragma unroll
            for (int i = 0; i < NB; ++i) STB(i, sq, kof);
        }
        // ---- phase 0 MFMA: acc[0..3] += af(kh0) x b0 ----
        __builtin_amdgcn_s_setprio(1);
#pragma unroll
        for (int m = 0; m < 4; ++m)
#pragma unroll
            for (int n = 0; n < 4; ++n)
                acc[m][n] = MFMA16(af[m], b0[n], acc[m][n]);
        __builtin_amdgcn_s_setprio(0);
        __builtin_amdgcn_sched_barrier(0);

        if constexpr (MFRAG == 8) {
            // ---- phase 1 reads (m0-3 kh1), MFMA acc[4..7] += ag(kh0) x b0 --
#pragma unroll
            for (int m = 0; m < 4; ++m) af[m] = *(const bf16x8*)(aB + m * 2048 + offK1);
            __builtin_amdgcn_s_setprio(1);
#pragma unroll
            for (int m = 0; m < 4; ++m)
#pragma unroll
                for (int n = 0; n < 4; ++n)
                    acc[4 + m][n] = MFMA16(ag[m], b0[n], acc[4 + m][n]);
            __builtin_amdgcn_s_setprio(0);
            __builtin_amdgcn_sched_barrier(0);
            // ---- phase 2 reads (m4-7 kh1), MFMA acc[0..3] += af(kh1) x b1 --
#pragma unroll
            for (int m = 0; m < 4; ++m)
                ag[m] = *(const bf16x8*)(aB + 8192 + m * 2048 + offK1);
            __builtin_amdgcn_s_setprio(1);
#pragma unroll
            for (int m = 0; m < 4; ++m)
#pragma unroll
                for (int n = 0; n < 4; ++n)
                    acc[m][n] = MFMA16(af[m], b1[n], acc[m][n]);
            __builtin_amdgcn_s_setprio(0);
            __builtin_amdgcn_sched_barrier(0);
            // ---- phase 3 MFMA: acc[4..7] += ag(kh1) x b1 ----
            __builtin_amdgcn_s_setprio(1);
#pragma unroll
            for (int m = 0; m < 4; ++m)
#pragma unroll
                for (int n = 0; n < 4; ++n)
                    acc[4 + m][n] = MFMA16(ag[m], b1[n], acc[4 + m][n]);
            __builtin_amdgcn_s_setprio(0);
        } else {
            // ---- phase 1 MFMA: acc[0..3] += ag(kh1) x b1 ----
            __builtin_amdgcn_s_setprio(1);
#pragma unroll
            for (int m = 0; m < 4; ++m)
#pragma unroll
                for (int n = 0; n < 4; ++n)
                    acc[m][n] = MFMA16(ag[m], b1[n], acc[m][n]);
            __builtin_amdgcn_s_setprio(0);
        }
        // ---- single end-of-tile sync: staged tile t+1 landed, reads done ---
        __builtin_amdgcn_sched_barrier(0);
        asm volatile("s_waitcnt vmcnt(0)" ::: "memory");
        pin_barrier();
    }
#undef STA
#undef STB

    // ---- epilogue: LDS-restage -> full-line coalesced stores ----
    {
        char* cst = smem;
        const int g4 = (lane >> 4) << 2, cl = lane & 15;
#pragma unroll
        for (int n = 0; n < 4; ++n) {
            int col = wc * 64 + n * 16 + cl;
            float bs = bias0[col0 + col];
            if (bias1) bs += bias1[col0 + col];
            if (bias2) bs += bias2[col0 + col];
#pragma unroll
            for (int m = 0; m < MFRAG; ++m) {
#pragma unroll
                for (int r = 0; r < 4; ++r) {
                    int row = wr * (MFRAG * 16) + m * 16 + g4 + r;
                    float v = acc[m][n][r] + bs;
                    if (BF16OUT) {
                        int scol = col ^ (((row >> 2) & 3) << 3);
                        *(u16*)(cst + row * 512 + scol * 2) = f2bf(v);
                    } else {
                        int scol = col ^ (((row >> 2) & 3) << 2);
                        *(float*)(cst + row * 512 + scol * 4) = v;
                    }
                }
            }
        }
        pin_barrier();
        const int esz = BF16OUT ? 2 : 4;
#pragma unroll
        for (int it = 0; it < 16; ++it) {
            int id = it * 512 + tid;       // 16B chunk: row*32 + c16
            int row = id >> 5, c16 = id & 31;
            int sc16 = c16 ^ ((row >> 2) & 3);
            u16x8 v = *(const u16x8*)(cst + row * 512 + sc16 * 16);
            char* dst = (char*)C + ((size_t)(row0 + row) * ldc + col0) * esz + c16 * 16;
            *(u16x8*)dst = v;
        }
    }
}

// ---------------- attention: one block per (b, segment, head) ---------------
template <int S>
__global__ __launch_bounds__(256) void k_attn(const u16* __restrict__ qkv,
                                              u16* __restrict__ ab, int layer) {
    constexpr int NCT = S / 16;
    constexpr int RPW = (S == 32) ? 1 : S / 64;
    constexpr int ACTIVE = (S == 32) ? 2 : 4;
    constexpr int KST = S / 32;
    constexpr int VSTRIDE = 2 * S;
    constexpr int VMASK = VSTRIDE / 16 - 1;

    __shared__ __align__(16) char KS[S * 128];
    __shared__ __align__(16) char VTS[64 * VSTRIDE];
    __shared__ __align__(16) char PS[S * VSTRIDE];

    const int per_b = (4096 / S) * 16;
    const int b = blockIdx.x / per_b;
    const int r0 = blockIdx.x % per_b;
    const int n = r0 >> 4, h = r0 & 15;
    const int token0 = b * 4096 + n * S;
    const int colQ = layer * 3072 + h * 64;
    const int tid = threadIdx.x, lane = tid & 63, wave = tid >> 6;

    constexpr int CHUNKS = S / 32;
#pragma unroll
    for (int c = 0; c < CHUNKS; ++c) {
        int lc = c * 256 + tid;
        int row = lc >> 3, off = (lc & 7) * 16;
        const char* base = (const char*)qkv + ((size_t)(token0 + row) * 9216 + colQ) * 2 + off;
        u16x8 kv = *(const u16x8*)(base + 1024 * 2);
        *(u16x8*)(KS + row * 128 + (off ^ ((row & 7) << 4))) = kv;
        u16x8 vv = *(const u16x8*)(base + 2048 * 2);
        int cb = off >> 1;
#pragma unroll
        for (int e = 0; e < 8; ++e) {
            int col = cb + e;
            *(u16*)(VTS + col * VSTRIDE + ((row * 2) ^ ((col & VMASK) << 4))) = vv[e];
        }
    }
    __syncthreads();

    f32x4 sacc[RPW][NCT] = {};
    if (wave < ACTIVE) {
#pragma unroll
        for (int rl = 0; rl < RPW; ++rl) {
            int rt = wave * RPW + rl;
#pragma unroll
            for (int ks2 = 0; ks2 < 2; ++ks2) {
                int qrow = token0 + rt * 16 + (lane & 15);
                int kbyte = ks2 * 64 + ((lane >> 4) << 4);
                bf16x8 aq = *(const bf16x8*)((const char*)qkv +
                              ((size_t)qrow * 9216 + colQ) * 2 + kbyte);
#pragma unroll
                for (int ct = 0; ct < NCT; ++ct) {
                    int krow = ct * 16 + (lane & 15);
                    bf16x8 bk = *(const bf16x8*)(KS + krow * 128 + (kbyte ^ ((krow & 7) << 4)));
                    sacc[rl][ct] = MFMA16(aq, bk, sacc[rl][ct]);
                }
            }
        }
#pragma unroll
        for (int rl = 0; rl < RPW; ++rl) {
            int rt = wave * RPW + rl;
#pragma unroll
            for (int r = 0; r < 4; ++r) {
                float vals[NCT];
                float m = -1e30f;
#pragma unroll
                for (int ct = 0; ct < NCT; ++ct) {
                    vals[ct] = sacc[rl][ct][r] * 0.125f;
                    m = fmaxf(m, vals[ct]);
                }
#pragma unroll
                for (int d = 1; d < 16; d <<= 1) m = fmaxf(m, __shfl_xor(m, d, 64));
                float sum = 0.f;
#pragma unroll
                for (int ct = 0; ct < NCT; ++ct) {
                    float p = exp2f((vals[ct] - m) * 1.44269504f);
                    vals[ct] = p;
                    sum += p;
                }
#pragma unroll
                for (int d = 1; d < 16; d <<= 1) sum += __shfl_xor(sum, d, 64);
                float inv = 1.0f / sum;
                int row = rt * 16 + ((lane >> 4) << 2) + r;
#pragma unroll
                for (int ct = 0; ct < NCT; ++ct) {
                    int col = ct * 16 + (lane & 15);
                    *(u16*)(PS + row * VSTRIDE + ((col * 2) ^ ((row & VMASK) << 4))) =
                        f2bf(vals[ct] * inv);
                }
            }
        }
    }
    __syncthreads();

    if (wave < ACTIVE) {
        const int colA = layer * 1024 + h * 64;
#pragma unroll
        for (int rl = 0; rl < RPW; ++rl) {
            int rt = wave * RPW + rl;
            f32x4 oacc[4] = {};
#pragma unroll
            for (int ks2 = 0; ks2 < KST; ++ks2) {
                int kbyte = ks2 * 64 + ((lane >> 4) << 4);
                int prow = rt * 16 + (lane & 15);
                bf16x8 ap = *(const bf16x8*)(PS + prow * VSTRIDE + (kbyte ^ ((prow & VMASK) << 4)));
#pragma unroll
                for (int ct = 0; ct < 4; ++ct) {
                    int vcol = ct * 16 + (lane & 15);
                    bf16x8 bv = *(const bf16x8*)(VTS + vcol * VSTRIDE + (kbyte ^ ((vcol & VMASK) << 4)));
                    oacc[ct] = MFMA16(ap, bv, oacc[ct]);
                }
            }
#pragma unroll
            for (int ct = 0; ct < 4; ++ct) {
#pragma unroll
                for (int r = 0; r < 4; ++r) {
                    int row = token0 + rt * 16 + ((lane >> 4) << 2) + r;
                    int col = colA + ct * 16 + (lane & 15);
                    ab[(size_t)row * 3072 + col] = f2bf(oacc[ct][r]);
                }
            }
        }
    }
}

// ---------------------------------------------------------------------------
extern "C" void kernel_launch(void* const* d_in, const int* in_sizes, int n_in,
                              void* d_out, int out_size, void* d_ws, size_t ws_size,
                              hipStream_t stream) {
    const float* x    = (const float*)d_in[0];
    const float* Wqkv = (const float*)d_in[1];
    const float* bqkv = (const float*)d_in[2];
    const float* Wo   = (const float*)d_in[3];
    const float* bo   = (const float*)d_in[4];

    char* ws = (char*)d_ws;
    u16* XE    = (u16*)(ws);                       // [8192][1024]
    u16* WQKVT = (u16*)(ws + 16777216);            // [9216][1024]
    u16* WOT   = (u16*)(ws + 35651584);            // [1024][3072]
    u16* QKVB  = (u16*)(ws + 41943040);            // [8192][9216]
    u16* ABUF  = (u16*)(ws + 192937984);           // [8192][3072]

    k_prep_xe<<<8192, 256, 0, stream>>>(x, XE);
    k_transpose_cast<<<dim3(16, 48, 3), 256, 0, stream>>>(
        Wqkv, WQKVT, 3072, (size_t)1024 * 3072, 1024, 3072, 0);
    k_transpose_cast<<<dim3(16, 16, 3), 256, 0, stream>>>(
        Wo, WOT, 1024, (size_t)1024 * 1024, 3072, 0, 1024);

    // QKV projection for all 3 layers: [8192,1024] @ [1024,9216]
    // grid = 32 x 36 = 1152 blocks (bx fastest: mask 31, shift 5)
    k_gemm4<256, true><<<dim3(1152), 512, 0, stream>>>(
        XE, WQKVT, QKVB, bqkv, nullptr, nullptr, 1024, 1024, 1024, 9216, 31, 5);

    // dilated segment attention per layer
    k_attn<32><<<4096, 256, 0, stream>>>(QKVB, ABUF, 0);
    k_attn<64><<<2048, 256, 0, stream>>>(QKVB, ABUF, 1);
    k_attn<128><<<1024, 256, 0, stream>>>(QKVB, ABUF, 2);

    // fused output projection + layer sum: [8192,3072] @ [3072,1024]
    // grid = 32 x 8 = 256 blocks
    k_gemm4<128, false><<<dim3(256), 512, 0, stream>>>(
        ABUF, WOT, d_out, bo, bo + 1024, bo + 2048, 3072, 3072, 3072, 1024, 31, 5);
}